// Round 11
// baseline (95.827 us; speedup 1.0000x reference)
//
#include <hip/hip_runtime.h>
#include <math.h>

#define ALPHA 0.7f
#define BETTA 0.3f
#define EPS   1e-8f

#define BLOCK 256
#define TILE_ROWS  1024                   // rows per block (2 phases x 512)
#define PHASE_ROWS 512
#define PHASE_F2   768                    // float2 per input per phase
#define TILE_F2    1536                   // float2 per input per tile
#define LDS_DW     1792                   // 1536 dw + 1 pad per 6 (256)

__device__ __forceinline__ void row_contrib(float x1, float y1, float z1,
                                            float x2, float y2, float z2,
                                            float& a0, float& a1, float& a2,
                                            float& ac) {
    float q1 = x1 * x1 + y1 * y1 + z1 * z1;
    float m = (q1 > EPS * EPS) ? 1.0f : 0.0f;
    float inv1 = (q1 > 0.0f) ? rsqrtf(q1) : 0.0f;
    float n1x = x1 * inv1, n1y = y1 * inv1, n1z = z1 * inv1;

    float q2 = x2 * x2 + y2 * y2 + z2 * z2;
    float inv2 = (q2 > 0.0f) ? rsqrtf(q2) : 0.0f;
    float u2x = x2 * inv2, u2y = y2 * inv2, u2z = z2 * inv2;

    float c = n1x * u2x + n1y * u2y + n1z * u2z;
    c = fminf(1.0f, fmaxf(-1.0f, c));
    float sin_a = sqrtf(fmaxf(0.0f, 1.0f - c * c));
    float cm1 = c - 1.0f;

    float d = n1x * x2 + n1y * y2 + n1z * z2;
    float wx = x2 - n1x * d, wy = y2 - n1y * d, wz = z2 - n1z * d;
    float wq = wx * wx + wy * wy + wz * wz;
    float invw = (wq > 0.0f) ? rsqrtf(wq) : 0.0f;
    float n2x = wx * invw, n2y = wy * invw, n2z = wz * invw;

    float s1 = n1x + n1y + n1z;
    float s2 = n2x + n2y + n2z;

    float tax = sin_a * (n2x * s1 - n1x * s2);
    float tay = sin_a * (n2y * s1 - n1y * s2);
    float taz = sin_a * (n2z * s1 - n1z * s2);

    float tbx = cm1 * (n1x * s1 + n2x * s2);
    float tby = cm1 * (n1y * s1 + n2y * s2);
    float tbz = cm1 * (n1z * s1 + n2z * s2);

    a0 += (ALPHA * tax * tax + BETTA * tbx * tbx) * m;
    a1 += (ALPHA * tay * tay + BETTA * tby * tby) * m;
    a2 += (ALPHA * taz * taz + BETTA * tbz * tbz) * m;
    ac += m;
}

// padded scatter: logical dword L -> physical L + L/6 (1 pad per 6 dwords).
// float2 store: L%6 in {0,2,4} so the pair never crosses a pad.
__device__ __forceinline__ void lds_store_f2(float* lds, int L0, float2 v) {
    int q = L0 / 6;                 // magic-mul
    int p = L0 + q;
    lds[p + 0] = v.x;
    lds[p + 1] = v.y;
}

// R9 structure (2048 one-shot blocks, coalesced loads, padded-LDS transpose)
// but LDS halved via two 512-row phases -> 14 KB/block -> 32 waves/CU
// resident (vs R9's 24). Phase-1 globals issue under phase-0 compute.
// Reads at 7t (7 coprime 32 -> 2-way = free). Per-wave partial store.
__global__ __launch_bounds__(BLOCK, 8) void trl_reduce(const float* __restrict__ v1,
                                                       const float* __restrict__ v2,
                                                       float4* __restrict__ ws,
                                                       int n_rows, int n_tiles) {
    __shared__ float ldsA[LDS_DW];  // 7 KB
    __shared__ float ldsB[LDS_DW];  // 7 KB

    int t = threadIdx.x;
    float a0 = 0.0f, a1 = 0.0f, a2 = 0.0f, ac = 0.0f;

    if (blockIdx.x < (unsigned)n_tiles) {
        const float2* g1 = (const float2*)v1;
        const float2* g2 = (const float2*)v2;
        long tb = (long)blockIdx.x * TILE_F2;

        // ---- phase 0 loads (coalesced f2: lane i -> base + j*256 + i)
        float2 A0 = g1[tb + 0 * BLOCK + t];
        float2 A1 = g1[tb + 1 * BLOCK + t];
        float2 A2 = g1[tb + 2 * BLOCK + t];
        float2 B0 = g2[tb + 0 * BLOCK + t];
        float2 B1 = g2[tb + 1 * BLOCK + t];
        float2 B2 = g2[tb + 2 * BLOCK + t];

        int u = 2 * t;
        lds_store_f2(ldsA, 0 * 512 + u, A0);
        lds_store_f2(ldsA, 1 * 512 + u, A1);
        lds_store_f2(ldsA, 2 * 512 + u, A2);
        lds_store_f2(ldsB, 0 * 512 + u, B0);
        lds_store_f2(ldsB, 1 * 512 + u, B1);
        lds_store_f2(ldsB, 2 * 512 + u, B2);
        __syncthreads();

        // ---- phase 0 LDS read (2 rows = 6 dw each input, contiguous at 7t)
        float fa[6], fb[6];
        int rb = 7 * t;
#pragma unroll
        for (int k = 0; k < 6; ++k) fa[k] = ldsA[rb + k];
#pragma unroll
        for (int k = 0; k < 6; ++k) fb[k] = ldsB[rb + k];

        // ---- phase 1 loads fly under phase 0 compute
        A0 = g1[tb + PHASE_F2 + 0 * BLOCK + t];
        A1 = g1[tb + PHASE_F2 + 1 * BLOCK + t];
        A2 = g1[tb + PHASE_F2 + 2 * BLOCK + t];
        B0 = g2[tb + PHASE_F2 + 0 * BLOCK + t];
        B1 = g2[tb + PHASE_F2 + 1 * BLOCK + t];
        B2 = g2[tb + PHASE_F2 + 2 * BLOCK + t];

        row_contrib(fa[0], fa[1], fa[2], fb[0], fb[1], fb[2], a0, a1, a2, ac);
        row_contrib(fa[3], fa[4], fa[5], fb[3], fb[4], fb[5], a0, a1, a2, ac);

        __syncthreads();  // all phase-0 reads complete before overwrite

        lds_store_f2(ldsA, 0 * 512 + u, A0);
        lds_store_f2(ldsA, 1 * 512 + u, A1);
        lds_store_f2(ldsA, 2 * 512 + u, A2);
        lds_store_f2(ldsB, 0 * 512 + u, B0);
        lds_store_f2(ldsB, 1 * 512 + u, B1);
        lds_store_f2(ldsB, 2 * 512 + u, B2);
        __syncthreads();

#pragma unroll
        for (int k = 0; k < 6; ++k) fa[k] = ldsA[rb + k];
#pragma unroll
        for (int k = 0; k < 6; ++k) fb[k] = ldsB[rb + k];

        row_contrib(fa[0], fa[1], fa[2], fb[0], fb[1], fb[2], a0, a1, a2, ac);
        row_contrib(fa[3], fa[4], fa[5], fb[3], fb[4], fb[5], a0, a1, a2, ac);
    }

    // tail rows beyond the last full tile (unused at N=2^21)
    if (blockIdx.x == 0) {
        for (long r = (long)n_tiles * TILE_ROWS + t; r < n_rows; r += BLOCK) {
            const float* q1 = v1 + r * 3;
            const float* q2 = v2 + r * 3;
            row_contrib(q1[0], q1[1], q1[2], q2[0], q2[1], q2[2], a0, a1, a2, ac);
        }
    }

    // per-wave shuffle reduction; lane0 of each wave stores its partial
    for (int off = 32; off > 0; off >>= 1) {
        a0 += __shfl_down(a0, off, 64);
        a1 += __shfl_down(a1, off, 64);
        a2 += __shfl_down(a2, off, 64);
        ac += __shfl_down(ac, off, 64);
    }
    int lane = t & 63;
    int wave = t >> 6;
    if (lane == 0) {
        float4 o;
        o.x = a0; o.y = a1; o.z = a2; o.w = ac;
        ws[(size_t)blockIdx.x * 4 + wave] = o;
    }
}

// Stage 2: one 256-thread block over nparts (= grid*4) float4 partials.
__global__ __launch_bounds__(256) void trl_final(const float4* __restrict__ ws,
                                                 float* __restrict__ out,
                                                 int nparts) {
    float s0 = 0.0f, s1 = 0.0f, s2 = 0.0f, sc = 0.0f;
    for (int i = threadIdx.x; i < nparts; i += 256) {
        float4 p = ws[i];
        s0 += p.x; s1 += p.y; s2 += p.z; sc += p.w;
    }
    for (int off = 32; off > 0; off >>= 1) {
        s0 += __shfl_down(s0, off, 64);
        s1 += __shfl_down(s1, off, 64);
        s2 += __shfl_down(s2, off, 64);
        sc += __shfl_down(sc, off, 64);
    }
    __shared__ float smem[4][4];
    int lane = threadIdx.x & 63;
    int wave = threadIdx.x >> 6;
    if (lane == 0) {
        smem[wave][0] = s0;
        smem[wave][1] = s1;
        smem[wave][2] = s2;
        smem[wave][3] = sc;
    }
    __syncthreads();
    if (threadIdx.x < 3) {
        float num = smem[0][threadIdx.x] + smem[1][threadIdx.x] +
                    smem[2][threadIdx.x] + smem[3][threadIdx.x];
        float cnt = smem[0][3] + smem[1][3] + smem[2][3] + smem[3][3];
        cnt = fmaxf(cnt, 1.0f);
        float v = num / cnt;
        if (isnan(v)) v = 0.0f;
        else if (isinf(v)) v = (v > 0.0f) ? 0.1f : -0.1f;
        out[threadIdx.x] = v;
    }
}

extern "C" void kernel_launch(void* const* d_in, const int* in_sizes, int n_in,
                              void* d_out, int out_size, void* d_ws, size_t ws_size,
                              hipStream_t stream) {
    const float* v1 = (const float*)d_in[0];
    const float* v2 = (const float*)d_in[1];
    float* out = (float*)d_out;
    float4* ws = (float4*)d_ws;

    int n_rows = in_sizes[0] / 3;
    int n_tiles = n_rows / TILE_ROWS;   // 2048 full tiles for N=2^21
    int grid = (n_tiles > 0) ? n_tiles : 1;

    trl_reduce<<<grid, BLOCK, 0, stream>>>(v1, v2, ws, n_rows, n_tiles);
    trl_final<<<1, 256, 0, stream>>>(ws, out, grid * 4);
}

// Round 12
// 93.975 us; speedup vs baseline: 1.0197x; 1.0197x over previous
//
#include <hip/hip_runtime.h>
#include <math.h>

#define ALPHA 0.7f
#define BETTA 0.3f
#define EPS   1e-8f

#define BLOCK 256
#define RPT   4                          // rows per thread
#define TILE_ROWS (BLOCK * RPT)          // 1024 rows / block

// 12-byte packed row: loads compile to global_load_dwordx3 (12B/lane,
// wave covers 768B contiguous = 6 x 128B lines, full line utilization).
struct __align__(4) row3 { float x, y, z; };

__device__ __forceinline__ void row_contrib(float x1, float y1, float z1,
                                            float x2, float y2, float z2,
                                            float& a0, float& a1, float& a2,
                                            float& ac) {
    float q1 = x1 * x1 + y1 * y1 + z1 * z1;
    float m = (q1 > EPS * EPS) ? 1.0f : 0.0f;
    float inv1 = (q1 > 0.0f) ? rsqrtf(q1) : 0.0f;
    float n1x = x1 * inv1, n1y = y1 * inv1, n1z = z1 * inv1;

    float q2 = x2 * x2 + y2 * y2 + z2 * z2;
    float inv2 = (q2 > 0.0f) ? rsqrtf(q2) : 0.0f;
    float u2x = x2 * inv2, u2y = y2 * inv2, u2z = z2 * inv2;

    float c = n1x * u2x + n1y * u2y + n1z * u2z;
    c = fminf(1.0f, fmaxf(-1.0f, c));
    float sin_a = sqrtf(fmaxf(0.0f, 1.0f - c * c));
    float cm1 = c - 1.0f;

    float d = n1x * x2 + n1y * y2 + n1z * z2;
    float wx = x2 - n1x * d, wy = y2 - n1y * d, wz = z2 - n1z * d;
    float wq = wx * wx + wy * wy + wz * wz;
    float invw = (wq > 0.0f) ? rsqrtf(wq) : 0.0f;
    float n2x = wx * invw, n2y = wy * invw, n2z = wz * invw;

    float s1 = n1x + n1y + n1z;
    float s2 = n2x + n2y + n2z;

    float tax = sin_a * (n2x * s1 - n1x * s2);
    float tay = sin_a * (n2y * s1 - n1y * s2);
    float taz = sin_a * (n2z * s1 - n1z * s2);

    float tbx = cm1 * (n1x * s1 + n2x * s2);
    float tby = cm1 * (n1y * s1 + n2y * s2);
    float tbz = cm1 * (n1z * s1 + n2z * s2);

    a0 += (ALPHA * tax * tax + BETTA * tbx * tbx) * m;
    a1 += (ALPHA * tay * tay + BETTA * tby * tby) * m;
    a2 += (ALPHA * tbz * 0.0f + ALPHA * taz * taz + BETTA * tbz * tbz) * m;
    ac += m;
}

// Direct dwordx3 row loads: lane i gets a complete row in registers.
// No LDS, no transpose, NO barriers — each thread issues 8 independent
// 12B loads (4 rows x 2 inputs) then computes. 2048 one-shot blocks.
// Rows interleaved so each k-step is wave-contiguous: row = tile + k*256 + t.
__global__ __launch_bounds__(BLOCK) void trl_reduce(const float* __restrict__ v1,
                                                    const float* __restrict__ v2,
                                                    float4* __restrict__ ws,
                                                    int n_rows, int n_tiles) {
    int t = threadIdx.x;
    float a0 = 0.0f, a1 = 0.0f, a2 = 0.0f, ac = 0.0f;

    if (blockIdx.x < (unsigned)n_tiles) {
        const row3* r1 = (const row3*)v1;
        const row3* r2 = (const row3*)v2;
        long base = (long)blockIdx.x * TILE_ROWS + t;

        row3 A[RPT], B[RPT];
#pragma unroll
        for (int k = 0; k < RPT; ++k) A[k] = r1[base + k * BLOCK];
#pragma unroll
        for (int k = 0; k < RPT; ++k) B[k] = r2[base + k * BLOCK];

#pragma unroll
        for (int k = 0; k < RPT; ++k)
            row_contrib(A[k].x, A[k].y, A[k].z, B[k].x, B[k].y, B[k].z,
                        a0, a1, a2, ac);
    }

    // tail rows beyond the last full tile (unused at N=2^21)
    if (blockIdx.x == 0) {
        for (long r = (long)n_tiles * TILE_ROWS + t; r < n_rows; r += BLOCK) {
            const float* q1 = v1 + r * 3;
            const float* q2 = v2 + r * 3;
            row_contrib(q1[0], q1[1], q1[2], q2[0], q2[1], q2[2], a0, a1, a2, ac);
        }
    }

    // per-wave shuffle reduction; lane0 of each wave stores its partial.
    for (int off = 32; off > 0; off >>= 1) {
        a0 += __shfl_down(a0, off, 64);
        a1 += __shfl_down(a1, off, 64);
        a2 += __shfl_down(a2, off, 64);
        ac += __shfl_down(ac, off, 64);
    }
    int lane = t & 63;
    int wave = t >> 6;
    if (lane == 0) {
        float4 o;
        o.x = a0; o.y = a1; o.z = a2; o.w = ac;
        ws[(size_t)blockIdx.x * 4 + wave] = o;
    }
}

// Stage 2: one 256-thread block over nparts (= grid*4) float4 partials.
__global__ __launch_bounds__(256) void trl_final(const float4* __restrict__ ws,
                                                 float* __restrict__ out,
                                                 int nparts) {
    float s0 = 0.0f, s1 = 0.0f, s2 = 0.0f, sc = 0.0f;
    for (int i = threadIdx.x; i < nparts; i += 256) {
        float4 p = ws[i];
        s0 += p.x; s1 += p.y; s2 += p.z; sc += p.w;
    }
    for (int off = 32; off > 0; off >>= 1) {
        s0 += __shfl_down(s0, off, 64);
        s1 += __shfl_down(s1, off, 64);
        s2 += __shfl_down(s2, off, 64);
        sc += __shfl_down(sc, off, 64);
    }
    __shared__ float smem[4][4];
    int lane = threadIdx.x & 63;
    int wave = threadIdx.x >> 6;
    if (lane == 0) {
        smem[wave][0] = s0;
        smem[wave][1] = s1;
        smem[wave][2] = s2;
        smem[wave][3] = sc;
    }
    __syncthreads();
    if (threadIdx.x < 3) {
        float num = smem[0][threadIdx.x] + smem[1][threadIdx.x] +
                    smem[2][threadIdx.x] + smem[3][threadIdx.x];
        float cnt = smem[0][3] + smem[1][3] + smem[2][3] + smem[3][3];
        cnt = fmaxf(cnt, 1.0f);
        float v = num / cnt;
        if (isnan(v)) v = 0.0f;
        else if (isinf(v)) v = (v > 0.0f) ? 0.1f : -0.1f;
        out[threadIdx.x] = v;
    }
}

extern "C" void kernel_launch(void* const* d_in, const int* in_sizes, int n_in,
                              void* d_out, int out_size, void* d_ws, size_t ws_size,
                              hipStream_t stream) {
    const float* v1 = (const float*)d_in[0];
    const float* v2 = (const float*)d_in[1];
    float* out = (float*)d_out;
    float4* ws = (float4*)d_ws;

    int n_rows = in_sizes[0] / 3;
    int n_tiles = n_rows / TILE_ROWS;   // 2048 full tiles for N=2^21
    int grid = (n_tiles > 0) ? n_tiles : 1;

    trl_reduce<<<grid, BLOCK, 0, stream>>>(v1, v2, ws, n_rows, n_tiles);
    trl_final<<<1, 256, 0, stream>>>(ws, out, grid * 4);
}